// Round 5
// baseline (367.733 us; speedup 1.0000x reference)
//
#include <hip/hip_runtime.h>
#include <hip/hip_bf16.h>
#include <math.h>

#define N_NODES 50000
#define N_EDGES 800000
#define D_FEAT  128
#define EPSF    1e-12f

// ---------------- workspace layout (bytes) ----------------
#define OFF_U2     0         // 512
#define OFF_S      4096      // 200000
#define OFF_SMAX   208896    // 200000 (encoded uint) -- memset together with row_ptr
#define OFF_ROWPTR 408896    // 200004
#define OFF_CURSOR 608960    // 200000
#define OFF_WTN    808960    // 32768 bf16 W_node^T
#define OFF_WTG    841728    // 32768 bf16 W_neigh^T
#define OFF_SSRC   874496    // 3200000
#define OFF_HB     4074496   // 12800000 bf16 h
#define OFF_AGGB   16874496  // 12800000 bf16 agg   (total 29.7 MB)

typedef __attribute__((ext_vector_type(8))) short bf8;
typedef __attribute__((ext_vector_type(4))) float f4;

// u2[k] = sum_j W_coef[k][j] * W_red[128+j]
__global__ void make_u2_kernel(const float* __restrict__ W_coef,
                               const float* __restrict__ W_red,
                               float* __restrict__ u2) {
    __shared__ float wr[128];
    int k = threadIdx.x;  // 128 threads
    wr[k] = W_red[128 + k];
    __syncthreads();
    const float4* row = (const float4*)(W_coef + k * 128);
    float acc = 0.f;
    #pragma unroll
    for (int j = 0; j < 32; ++j) {
        float4 v = row[j];
        acc += v.x * wr[4*j] + v.y * wr[4*j+1] + v.z * wr[4*j+2] + v.w * wr[4*j+3];
    }
    u2[k] = acc;
}

// Fused: blocks [0,12500): wave-per-node -> s[v]=dot(h[v],u2) (f32) + hb[v]=bf16(h[v]).
//        blocks [12500,12564): transpose W_node/W_neigh to bf16 row-major-by-output.
__global__ __launch_bounds__(256) void prep_kernel(
        const float* __restrict__ h, const float* __restrict__ u2,
        const float* __restrict__ Wn, const float* __restrict__ Wg,
        float* __restrict__ s, unsigned short* __restrict__ hb,
        unsigned short* __restrict__ WtN, unsigned short* __restrict__ WtG) {
    int b = blockIdx.x;
    if (b < 12500) {
        int node = b * 4 + (threadIdx.x >> 6);   // 50000 = 12500*4 exactly
        int lane = threadIdx.x & 63;
        float2 hv = ((const float2*)(h + (size_t)node * 128))[lane];
        float2 uv = ((const float2*)u2)[lane];
        float v = hv.x * uv.x + hv.y * uv.y;
        #pragma unroll
        for (int off = 32; off; off >>= 1) v += __shfl_xor(v, off);
        if (lane == 0) s[node] = v;
        __hip_bfloat162 p = __float22bfloat162_rn(hv);
        ((unsigned int*)(hb + (size_t)node * 128))[lane] = *(unsigned int*)&p;
    } else {
        int idx = (b - 12500) * 256 + threadIdx.x;   // 0..16383
        int n = idx >> 7, k = idx & 127;
        __hip_bfloat16 a = __float2bfloat16(Wn[k * 128 + n]);
        __hip_bfloat16 g = __float2bfloat16(Wg[k * 128 + n]);
        WtN[n * 128 + k] = *(unsigned short*)&a;
        WtG[n * 128 + k] = *(unsigned short*)&g;
    }
}

__global__ void hist_kernel(const int* __restrict__ dst, int* __restrict__ row_ptr) {
    int e = blockIdx.x * blockDim.x + threadIdx.x;
    if (e < N_EDGES) atomicAdd(&row_ptr[dst[e]], 1);
}

// single-block exclusive scan; also writes cursor copy and total at data[n]
__global__ __launch_bounds__(1024) void scan_kernel(int* __restrict__ data,
                                                    int* __restrict__ cursor, int n) {
    const int EPT = 49;  // 1024*49 = 50176 >= 50000
    int tid = threadIdx.x;
    int lane = tid & 63, wid = tid >> 6;
    int base = tid * EPT;
    int vals[EPT];
    int local = 0;
    #pragma unroll
    for (int i = 0; i < EPT; ++i) {
        int id = base + i;
        vals[i] = (id < n) ? data[id] : 0;
        local += vals[i];
    }
    int incl = local;
    #pragma unroll
    for (int off = 1; off < 64; off <<= 1) {
        int t = __shfl_up(incl, off);
        if (lane >= off) incl += t;
    }
    __shared__ int wsum[16];
    if (lane == 63) wsum[wid] = incl;
    __syncthreads();
    if (tid < 16) {
        int v = wsum[tid];
        int s2 = v;
        #pragma unroll
        for (int off = 1; off < 16; off <<= 1) {
            int t = __shfl_up(s2, off);
            if (tid >= off) s2 += t;
        }
        wsum[tid] = s2 - v;
    }
    __syncthreads();
    int excl = wsum[wid] + (incl - local);
    #pragma unroll
    for (int i = 0; i < EPT; ++i) {
        int id = base + i;
        if (id < n) { data[id] = excl; cursor[id] = excl; }
        excl += vals[i];
    }
    if (tid == 1023) data[n] = excl;
}

// CSR scatter + order-encoded segment-max of s[src] per dst
__global__ void scatter_kernel(const int* __restrict__ src, const int* __restrict__ dst,
                               const float* __restrict__ s,
                               int* __restrict__ cursor, int* __restrict__ ssrc,
                               unsigned int* __restrict__ smax) {
    int e = blockIdx.x * blockDim.x + threadIdx.x;
    if (e < N_EDGES) {
        int d = dst[e];
        int sv = src[e];
        int p = atomicAdd(&cursor[d], 1);
        ssrc[p] = sv;
        unsigned b = __float_as_uint(s[sv]);
        unsigned enc = (b & 0x80000000u) ? ~b : (b | 0x80000000u);  // order-preserving
        atomicMax(&smax[d], enc);
    }
}

// one wave per node, single pass: 4 edges/iter, 16-lane groups each load one
// full 256B bf16 h-row (16B/lane). Lane (q,l16) owns features l16*8..+7 for
// edges e%4==q; cross-q combine at the end. Writes agg as bf16.
__global__ __launch_bounds__(256) void aggregate_kernel(
        const int* __restrict__ row_ptr, const int* __restrict__ ssrc,
        const float* __restrict__ s, const unsigned int* __restrict__ smax,
        const unsigned short* __restrict__ hb,
        unsigned short* __restrict__ aggb) {
    int node = blockIdx.x * 4 + (threadIdx.x >> 6);
    int lane = threadIdx.x & 63;
    if (node >= N_NODES) return;
    int beg = row_ptr[node];
    int deg = row_ptr[node + 1] - beg;
    int q = lane >> 4, l16 = lane & 15;

    unsigned eu = smax[node];
    unsigned mbits = (eu & 0x80000000u) ? (eu ^ 0x80000000u) : ~eu;
    float m = __uint_as_float(mbits);   // valid whenever deg>0

    float acc[8] = {0.f, 0.f, 0.f, 0.f, 0.f, 0.f, 0.f, 0.f};
    float denom = 0.f;
    for (int base = 0; base < deg; base += 64) {
        int cnt = min(64, deg - base);
        int esrc = 0;
        float w_l = 0.f;
        if (lane < cnt) {
            esrc = ssrc[beg + base + lane];
            w_l = __expf(s[esrc] - m);
        }
        denom += w_l;
        int groups = (cnt + 3) >> 2;
        for (int j = 0; j < groups; ++j) {
            int e = 4 * j + q;
            int ec = min(e, cnt - 1);
            int bsrc = __shfl(esrc, ec);
            float w = __shfl(w_l, ec);
            if (e >= cnt) w = 0.f;
            uint4 hv = *(const uint4*)(hb + (size_t)bsrc * 128 + l16 * 8);
            acc[0] = fmaf(w, __uint_as_float(hv.x << 16),        acc[0]);
            acc[1] = fmaf(w, __uint_as_float(hv.x & 0xFFFF0000u), acc[1]);
            acc[2] = fmaf(w, __uint_as_float(hv.y << 16),        acc[2]);
            acc[3] = fmaf(w, __uint_as_float(hv.y & 0xFFFF0000u), acc[3]);
            acc[4] = fmaf(w, __uint_as_float(hv.z << 16),        acc[4]);
            acc[5] = fmaf(w, __uint_as_float(hv.z & 0xFFFF0000u), acc[5]);
            acc[6] = fmaf(w, __uint_as_float(hv.w << 16),        acc[6]);
            acc[7] = fmaf(w, __uint_as_float(hv.w & 0xFFFF0000u), acc[7]);
        }
    }
    #pragma unroll
    for (int i = 0; i < 8; ++i) {
        acc[i] += __shfl_xor(acc[i], 16);
        acc[i] += __shfl_xor(acc[i], 32);
    }
    #pragma unroll
    for (int off = 32; off; off >>= 1) denom += __shfl_xor(denom, off);
    float inv = 1.f / (denom + EPSF);
    if (q == 0) {
        unsigned o[4];
        #pragma unroll
        for (int i = 0; i < 4; ++i) {
            __hip_bfloat162 p = __float22bfloat162_rn(
                make_float2(acc[2*i] * inv, acc[2*i+1] * inv));
            o[i] = *(unsigned*)&p;
        }
        *(uint4*)(aggb + (size_t)node * 128 + l16 * 8) = make_uint4(o[0], o[1], o[2], o[3]);
    }
}

// out[v] = normalize([h[v]@W_node + b_node, agg[v]@W_neigh + b_neigh])
// MFMA 16x16x32 bf16; wave owns 16 rows x all 256 cols; no LDS, no barriers.
// A and B fragments load directly as bf16 (16B) -- zero conversion VALU.
__global__ __launch_bounds__(256) void gemm_norm_mfma(
        const unsigned short* __restrict__ hb, const unsigned short* __restrict__ aggb,
        const unsigned short* __restrict__ WtN, const unsigned short* __restrict__ WtG,
        const float* __restrict__ b_node, const float* __restrict__ b_neigh,
        float* __restrict__ out) {
    int wave = threadIdx.x >> 6;
    int lane = threadIdx.x & 63;
    int node0 = blockIdx.x * 64 + wave * 16;
    if (node0 >= N_NODES) return;           // 50000 % 16 == 0
    int quad = lane >> 4, l16 = lane & 15;
    int arow = node0 + l16;

    f4 accN[8], accG[8];
    #pragma unroll
    for (int t = 0; t < 8; ++t) {
        accN[t] = (f4){0.f, 0.f, 0.f, 0.f};
        accG[t] = (f4){0.f, 0.f, 0.f, 0.f};
    }

    #pragma unroll
    for (int kc = 0; kc < 4; ++kc) {
        int kbase = kc * 32 + quad * 8;
        bf8 aH = *(const bf8*)(hb   + (size_t)arow * 128 + kbase);
        bf8 aG = *(const bf8*)(aggb + (size_t)arow * 128 + kbase);
        #pragma unroll
        for (int t = 0; t < 8; ++t) {
            bf8 bN = *(const bf8*)(WtN + (size_t)(t * 16 + l16) * 128 + kbase);
            bf8 bG = *(const bf8*)(WtG + (size_t)(t * 16 + l16) * 128 + kbase);
            accN[t] = __builtin_amdgcn_mfma_f32_16x16x32_bf16(aH, bN, accN[t], 0, 0, 0);
            accG[t] = __builtin_amdgcn_mfma_f32_16x16x32_bf16(aG, bG, accG[t], 0, 0, 0);
        }
    }

    float ssr[4] = {0.f, 0.f, 0.f, 0.f};
    #pragma unroll
    for (int t = 0; t < 8; ++t) {
        float bn = b_node[t * 16 + l16];
        float bg = b_neigh[t * 16 + l16];
        #pragma unroll
        for (int r = 0; r < 4; ++r) {
            accN[t][r] += bn;
            accG[t][r] += bg;
            ssr[r] = fmaf(accN[t][r], accN[t][r], ssr[r]);
            ssr[r] = fmaf(accG[t][r], accG[t][r], ssr[r]);
        }
    }
    #pragma unroll
    for (int r = 0; r < 4; ++r) {
        ssr[r] += __shfl_xor(ssr[r], 1);
        ssr[r] += __shfl_xor(ssr[r], 2);
        ssr[r] += __shfl_xor(ssr[r], 4);
        ssr[r] += __shfl_xor(ssr[r], 8);
    }
    #pragma unroll
    for (int r = 0; r < 4; ++r) {
        float sc = rsqrtf(fmaxf(ssr[r], EPSF));
        size_t node = node0 + quad * 4 + r;   // C/D: row = quad*4 + reg
        float* o = out + node * 256;
        #pragma unroll
        for (int t = 0; t < 8; ++t) {
            o[t * 16 + l16]       = accN[t][r] * sc;
            o[128 + t * 16 + l16] = accG[t][r] * sc;
        }
    }
}

extern "C" void kernel_launch(void* const* d_in, const int* in_sizes, int n_in,
                              void* d_out, int out_size, void* d_ws, size_t ws_size,
                              hipStream_t stream) {
    const float* h       = (const float*)d_in[0];
    const int*   src     = (const int*)d_in[1];
    const int*   dst     = (const int*)d_in[2];
    const float* W_coef  = (const float*)d_in[3];
    // b_coef (d_in[4]) and b_red (d_in[6]) cancel under per-segment softmax shift-invariance
    const float* W_red   = (const float*)d_in[5];
    const float* W_node  = (const float*)d_in[7];
    const float* b_node  = (const float*)d_in[8];
    const float* W_neigh = (const float*)d_in[9];
    const float* b_neigh = (const float*)d_in[10];
    float* out = (float*)d_out;

    char* w = (char*)d_ws;
    float*          u2      = (float*)(w + OFF_U2);
    float*          s       = (float*)(w + OFF_S);
    unsigned int*   smax    = (unsigned int*)(w + OFF_SMAX);
    int*            row_ptr = (int*)(w + OFF_ROWPTR);
    int*            cursor  = (int*)(w + OFF_CURSOR);
    unsigned short* WtN     = (unsigned short*)(w + OFF_WTN);
    unsigned short* WtG     = (unsigned short*)(w + OFF_WTG);
    int*            ssrc    = (int*)(w + OFF_SSRC);
    unsigned short* hb      = (unsigned short*)(w + OFF_HB);
    unsigned short* aggb    = (unsigned short*)(w + OFF_AGGB);

    // smax and row_ptr are contiguous: one memset zeroes both
    hipMemsetAsync(w + OFF_SMAX, 0, (OFF_ROWPTR - OFF_SMAX) + (N_NODES + 1) * sizeof(int), stream);
    make_u2_kernel<<<1, 128, 0, stream>>>(W_coef, W_red, u2);
    prep_kernel<<<12564, 256, 0, stream>>>(h, u2, W_node, W_neigh, s, hb, WtN, WtG);
    hist_kernel<<<N_EDGES / 256, 256, 0, stream>>>(dst, row_ptr);
    scan_kernel<<<1, 1024, 0, stream>>>(row_ptr, cursor, N_NODES);
    scatter_kernel<<<N_EDGES / 256, 256, 0, stream>>>(src, dst, s, cursor, ssrc, smax);
    aggregate_kernel<<<N_NODES / 4, 256, 0, stream>>>(row_ptr, ssrc, s, smax, hb, aggb);
    gemm_norm_mfma<<<(N_NODES + 63) / 64, 256, 0, stream>>>(
        hb, aggb, WtN, WtG, b_node, b_neigh, out);
}

// Round 6
// 288.885 us; speedup vs baseline: 1.2729x; 1.2729x over previous
//
#include <hip/hip_runtime.h>
#include <hip/hip_bf16.h>
#include <math.h>

#define N_NODES 50000
#define N_EDGES 800000
#define D_FEAT  128
#define EPSF    1e-12f

// ---------------- workspace layout (bytes) ----------------
#define OFF_U2     0         // 512
#define OFF_PARTIAL 1024     // 1024 (256 ints, scan block partials)
#define OFF_S      4096      // 200000
#define OFF_SMAX   208896    // 200000 (encoded uint) -- memset together with row_ptr
#define OFF_ROWPTR 408896    // 200004
#define OFF_CURSOR 608960    // 200000
#define OFF_WTN    808960    // 32768 bf16 W_node^T
#define OFF_WTG    841728    // 32768 bf16 W_neigh^T
#define OFF_SSRC   874496    // 3200000
#define OFF_HB     4074496   // 12800000 bf16 h
#define OFF_AGGB   16874496  // 12800000 bf16 agg   (total 29.7 MB)

typedef __attribute__((ext_vector_type(8))) short bf8;
typedef __attribute__((ext_vector_type(4))) float f4;

// u2[k] = sum_j W_coef[k][j] * W_red[128+j]
__global__ void make_u2_kernel(const float* __restrict__ W_coef,
                               const float* __restrict__ W_red,
                               float* __restrict__ u2) {
    __shared__ float wr[128];
    int k = threadIdx.x;  // 128 threads
    wr[k] = W_red[128 + k];
    __syncthreads();
    const float4* row = (const float4*)(W_coef + k * 128);
    float acc = 0.f;
    #pragma unroll
    for (int j = 0; j < 32; ++j) {
        float4 v = row[j];
        acc += v.x * wr[4*j] + v.y * wr[4*j+1] + v.z * wr[4*j+2] + v.w * wr[4*j+3];
    }
    u2[k] = acc;
}

// Fused, three block roles (independent work overlapped in one dispatch):
//   [0,12500):      wave-per-node -> s[v]=dot(h[v],u2) f32 + hb[v]=bf16(h[v])
//   [12500,12564):  transpose W_node/W_neigh to bf16 output-major
//   [12564,15689):  edge histogram into row_ptr (atomicAdd)
__global__ __launch_bounds__(256) void prep_kernel(
        const float* __restrict__ h, const float* __restrict__ u2,
        const float* __restrict__ Wn, const float* __restrict__ Wg,
        const int* __restrict__ dst,
        float* __restrict__ s, unsigned short* __restrict__ hb,
        unsigned short* __restrict__ WtN, unsigned short* __restrict__ WtG,
        int* __restrict__ row_ptr) {
    int b = blockIdx.x;
    if (b < 12500) {
        int node = b * 4 + (threadIdx.x >> 6);   // 50000 = 12500*4 exactly
        int lane = threadIdx.x & 63;
        float2 hv = ((const float2*)(h + (size_t)node * 128))[lane];
        float2 uv = ((const float2*)u2)[lane];
        float v = hv.x * uv.x + hv.y * uv.y;
        #pragma unroll
        for (int off = 32; off; off >>= 1) v += __shfl_xor(v, off);
        if (lane == 0) s[node] = v;
        __hip_bfloat162 p = __float22bfloat162_rn(hv);
        ((unsigned int*)(hb + (size_t)node * 128))[lane] = *(unsigned int*)&p;
    } else if (b < 12564) {
        int idx = (b - 12500) * 256 + threadIdx.x;   // 0..16383
        int n = idx >> 7, k = idx & 127;
        __hip_bfloat16 a = __float2bfloat16(Wn[k * 128 + n]);
        __hip_bfloat16 g = __float2bfloat16(Wg[k * 128 + n]);
        WtN[n * 128 + k] = *(unsigned short*)&a;
        WtG[n * 128 + k] = *(unsigned short*)&g;
    } else {
        int e = (b - 12564) * 256 + threadIdx.x;     // 3125*256 = 800000 exactly
        if (e < N_EDGES) atomicAdd(&row_ptr[dst[e]], 1);
    }
}

// -------- 3-phase grid-parallel exclusive scan of the 50000-bin histogram -------
__global__ __launch_bounds__(256) void reduce_kernel(const int* __restrict__ hist,
                                                     int* __restrict__ partial) {
    int gid = blockIdx.x * 256 + threadIdx.x;
    int v = (gid < N_NODES) ? hist[gid] : 0;
    #pragma unroll
    for (int off = 32; off; off >>= 1) v += __shfl_down(v, off);
    __shared__ int ws[4];
    int lane = threadIdx.x & 63, wid = threadIdx.x >> 6;
    if (lane == 0) ws[wid] = v;
    __syncthreads();
    if (threadIdx.x == 0) partial[blockIdx.x] = ws[0] + ws[1] + ws[2] + ws[3];
}

__global__ __launch_bounds__(256) void scan_partials_kernel(int* __restrict__ partial,
                                                            int nb) {
    int tid = threadIdx.x;
    int lane = tid & 63, wid = tid >> 6;
    int v = (tid < nb) ? partial[tid] : 0;
    int incl = v;
    #pragma unroll
    for (int off = 1; off < 64; off <<= 1) {
        int t = __shfl_up(incl, off);
        if (lane >= off) incl += t;
    }
    __shared__ int ws[4];
    if (lane == 63) ws[wid] = incl;
    __syncthreads();
    __shared__ int wbase[4];
    if (tid < 4) {
        int b = 0;
        for (int i = 0; i < tid; ++i) b += ws[i];
        wbase[tid] = b;
    }
    __syncthreads();
    partial[tid] = wbase[wid] + incl - v;   // exclusive
}

// in-place hist->offsets; also writes cursor copy and row_ptr[n]
__global__ __launch_bounds__(256) void scan_apply_kernel(
        const int* __restrict__ partial,
        int* __restrict__ row_ptr, int* __restrict__ cursor) {
    int gid = blockIdx.x * 256 + threadIdx.x;
    int tid = threadIdx.x;
    int lane = tid & 63, wid = tid >> 6;
    int v = (gid < N_NODES) ? row_ptr[gid] : 0;
    int incl = v;
    #pragma unroll
    for (int off = 1; off < 64; off <<= 1) {
        int t = __shfl_up(incl, off);
        if (lane >= off) incl += t;
    }
    __shared__ int ws[4];
    if (lane == 63) ws[wid] = incl;
    __syncthreads();
    __shared__ int wbase[4];
    if (tid < 4) {
        int b = 0;
        for (int i = 0; i < tid; ++i) b += ws[i];
        wbase[tid] = b;
    }
    __syncthreads();
    int excl = partial[blockIdx.x] + wbase[wid] + incl - v;
    if (gid < N_NODES) { row_ptr[gid] = excl; cursor[gid] = excl; }
    if (gid == 0) row_ptr[N_NODES] = N_EDGES;
}

// CSR scatter + order-encoded segment-max of s[src] per dst
__global__ void scatter_kernel(const int* __restrict__ src, const int* __restrict__ dst,
                               const float* __restrict__ s,
                               int* __restrict__ cursor, int* __restrict__ ssrc,
                               unsigned int* __restrict__ smax) {
    int e = blockIdx.x * blockDim.x + threadIdx.x;
    if (e < N_EDGES) {
        int d = dst[e];
        int sv = src[e];
        int p = atomicAdd(&cursor[d], 1);
        ssrc[p] = sv;
        unsigned b = __float_as_uint(s[sv]);
        unsigned enc = (b & 0x80000000u) ? ~b : (b | 0x80000000u);  // order-preserving
        atomicMax(&smax[d], enc);
    }
}

// one wave per node, single pass: 4 edges/iter, 16-lane groups each load one
// full 256B bf16 h-row (16B/lane). Writes agg as bf16.
__global__ __launch_bounds__(256) void aggregate_kernel(
        const int* __restrict__ row_ptr, const int* __restrict__ ssrc,
        const float* __restrict__ s, const unsigned int* __restrict__ smax,
        const unsigned short* __restrict__ hb,
        unsigned short* __restrict__ aggb) {
    int node = blockIdx.x * 4 + (threadIdx.x >> 6);
    int lane = threadIdx.x & 63;
    if (node >= N_NODES) return;
    int beg = row_ptr[node];
    int deg = row_ptr[node + 1] - beg;
    int q = lane >> 4, l16 = lane & 15;

    unsigned eu = smax[node];
    unsigned mbits = (eu & 0x80000000u) ? (eu ^ 0x80000000u) : ~eu;
    float m = __uint_as_float(mbits);   // valid whenever deg>0

    float acc[8] = {0.f, 0.f, 0.f, 0.f, 0.f, 0.f, 0.f, 0.f};
    float denom = 0.f;
    for (int base = 0; base < deg; base += 64) {
        int cnt = min(64, deg - base);
        int esrc = 0;
        float w_l = 0.f;
        if (lane < cnt) {
            esrc = ssrc[beg + base + lane];
            w_l = __expf(s[esrc] - m);
        }
        denom += w_l;
        int groups = (cnt + 3) >> 2;
        for (int j = 0; j < groups; ++j) {
            int e = 4 * j + q;
            int ec = min(e, cnt - 1);
            int bsrc = __shfl(esrc, ec);
            float w = __shfl(w_l, ec);
            if (e >= cnt) w = 0.f;
            uint4 hv = *(const uint4*)(hb + (size_t)bsrc * 128 + l16 * 8);
            acc[0] = fmaf(w, __uint_as_float(hv.x << 16),        acc[0]);
            acc[1] = fmaf(w, __uint_as_float(hv.x & 0xFFFF0000u), acc[1]);
            acc[2] = fmaf(w, __uint_as_float(hv.y << 16),        acc[2]);
            acc[3] = fmaf(w, __uint_as_float(hv.y & 0xFFFF0000u), acc[3]);
            acc[4] = fmaf(w, __uint_as_float(hv.z << 16),        acc[4]);
            acc[5] = fmaf(w, __uint_as_float(hv.z & 0xFFFF0000u), acc[5]);
            acc[6] = fmaf(w, __uint_as_float(hv.w << 16),        acc[6]);
            acc[7] = fmaf(w, __uint_as_float(hv.w & 0xFFFF0000u), acc[7]);
        }
    }
    #pragma unroll
    for (int i = 0; i < 8; ++i) {
        acc[i] += __shfl_xor(acc[i], 16);
        acc[i] += __shfl_xor(acc[i], 32);
    }
    #pragma unroll
    for (int off = 32; off; off >>= 1) denom += __shfl_xor(denom, off);
    float inv = 1.f / (denom + EPSF);
    if (q == 0) {
        unsigned o[4];
        #pragma unroll
        for (int i = 0; i < 4; ++i) {
            __hip_bfloat162 p = __float22bfloat162_rn(
                make_float2(acc[2*i] * inv, acc[2*i+1] * inv));
            o[i] = *(unsigned*)&p;
        }
        *(uint4*)(aggb + (size_t)node * 128 + l16 * 8) = make_uint4(o[0], o[1], o[2], o[3]);
    }
}

// out[v] = normalize([h[v]@W_node + b_node, agg[v]@W_neigh + b_neigh])
// MFMA 16x16x32 bf16; wave owns 16 rows x all 256 cols; no LDS, no barriers.
__global__ __launch_bounds__(256) void gemm_norm_mfma(
        const unsigned short* __restrict__ hb, const unsigned short* __restrict__ aggb,
        const unsigned short* __restrict__ WtN, const unsigned short* __restrict__ WtG,
        const float* __restrict__ b_node, const float* __restrict__ b_neigh,
        float* __restrict__ out) {
    int wave = threadIdx.x >> 6;
    int lane = threadIdx.x & 63;
    int node0 = blockIdx.x * 64 + wave * 16;
    if (node0 >= N_NODES) return;           // 50000 % 16 == 0
    int quad = lane >> 4, l16 = lane & 15;
    int arow = node0 + l16;

    f4 accN[8], accG[8];
    #pragma unroll
    for (int t = 0; t < 8; ++t) {
        accN[t] = (f4){0.f, 0.f, 0.f, 0.f};
        accG[t] = (f4){0.f, 0.f, 0.f, 0.f};
    }

    #pragma unroll
    for (int kc = 0; kc < 4; ++kc) {
        int kbase = kc * 32 + quad * 8;
        bf8 aH = *(const bf8*)(hb   + (size_t)arow * 128 + kbase);
        bf8 aG = *(const bf8*)(aggb + (size_t)arow * 128 + kbase);
        #pragma unroll
        for (int t = 0; t < 8; ++t) {
            bf8 bN = *(const bf8*)(WtN + (size_t)(t * 16 + l16) * 128 + kbase);
            bf8 bG = *(const bf8*)(WtG + (size_t)(t * 16 + l16) * 128 + kbase);
            accN[t] = __builtin_amdgcn_mfma_f32_16x16x32_bf16(aH, bN, accN[t], 0, 0, 0);
            accG[t] = __builtin_amdgcn_mfma_f32_16x16x32_bf16(aG, bG, accG[t], 0, 0, 0);
        }
    }

    float ssr[4] = {0.f, 0.f, 0.f, 0.f};
    #pragma unroll
    for (int t = 0; t < 8; ++t) {
        float bn = b_node[t * 16 + l16];
        float bg = b_neigh[t * 16 + l16];
        #pragma unroll
        for (int r = 0; r < 4; ++r) {
            accN[t][r] += bn;
            accG[t][r] += bg;
            ssr[r] = fmaf(accN[t][r], accN[t][r], ssr[r]);
            ssr[r] = fmaf(accG[t][r], accG[t][r], ssr[r]);
        }
    }
    #pragma unroll
    for (int r = 0; r < 4; ++r) {
        ssr[r] += __shfl_xor(ssr[r], 1);
        ssr[r] += __shfl_xor(ssr[r], 2);
        ssr[r] += __shfl_xor(ssr[r], 4);
        ssr[r] += __shfl_xor(ssr[r], 8);
    }
    #pragma unroll
    for (int r = 0; r < 4; ++r) {
        float sc = rsqrtf(fmaxf(ssr[r], EPSF));
        size_t node = node0 + quad * 4 + r;   // C/D: row = quad*4 + reg
        float* o = out + node * 256;
        #pragma unroll
        for (int t = 0; t < 8; ++t) {
            o[t * 16 + l16]       = accN[t][r] * sc;
            o[128 + t * 16 + l16] = accG[t][r] * sc;
        }
    }
}

extern "C" void kernel_launch(void* const* d_in, const int* in_sizes, int n_in,
                              void* d_out, int out_size, void* d_ws, size_t ws_size,
                              hipStream_t stream) {
    const float* h       = (const float*)d_in[0];
    const int*   src     = (const int*)d_in[1];
    const int*   dst     = (const int*)d_in[2];
    const float* W_coef  = (const float*)d_in[3];
    // b_coef (d_in[4]) and b_red (d_in[6]) cancel under per-segment softmax shift-invariance
    const float* W_red   = (const float*)d_in[5];
    const float* W_node  = (const float*)d_in[7];
    const float* b_node  = (const float*)d_in[8];
    const float* W_neigh = (const float*)d_in[9];
    const float* b_neigh = (const float*)d_in[10];
    float* out = (float*)d_out;

    char* w = (char*)d_ws;
    float*          u2      = (float*)(w + OFF_U2);
    int*            partial = (int*)(w + OFF_PARTIAL);
    float*          s       = (float*)(w + OFF_S);
    unsigned int*   smax    = (unsigned int*)(w + OFF_SMAX);
    int*            row_ptr = (int*)(w + OFF_ROWPTR);
    int*            cursor  = (int*)(w + OFF_CURSOR);
    unsigned short* WtN     = (unsigned short*)(w + OFF_WTN);
    unsigned short* WtG     = (unsigned short*)(w + OFF_WTG);
    int*            ssrc    = (int*)(w + OFF_SSRC);
    unsigned short* hb      = (unsigned short*)(w + OFF_HB);
    unsigned short* aggb    = (unsigned short*)(w + OFF_AGGB);

    const int NB = (N_NODES + 255) / 256;   // 196 scan blocks

    // smax and row_ptr are contiguous: one memset zeroes both
    hipMemsetAsync(w + OFF_SMAX, 0, (OFF_ROWPTR - OFF_SMAX) + (N_NODES + 1) * sizeof(int), stream);
    make_u2_kernel<<<1, 128, 0, stream>>>(W_coef, W_red, u2);
    prep_kernel<<<15689, 256, 0, stream>>>(h, u2, W_node, W_neigh, dst,
                                           s, hb, WtN, WtG, row_ptr);
    reduce_kernel<<<NB, 256, 0, stream>>>(row_ptr, partial);
    scan_partials_kernel<<<1, 256, 0, stream>>>(partial, NB);
    scan_apply_kernel<<<NB, 256, 0, stream>>>(partial, row_ptr, cursor);
    scatter_kernel<<<N_EDGES / 256, 256, 0, stream>>>(src, dst, s, cursor, ssrc, smax);
    aggregate_kernel<<<N_NODES / 4, 256, 0, stream>>>(row_ptr, ssrc, s, smax, hb, aggb);
    gemm_norm_mfma<<<(N_NODES + 63) / 64, 256, 0, stream>>>(
        hb, aggb, WtN, WtG, b_node, b_neigh, out);
}